// Round 13
// baseline (253.572 us; speedup 1.0000x reference)
//
#include <hip/hip_runtime.h>

typedef unsigned short ushort_t;
typedef __attribute__((ext_vector_type(8))) short short8;
typedef __attribute__((ext_vector_type(8))) __bf16 bf16x8;
typedef __attribute__((ext_vector_type(4))) float floatx4;

#define NN 96
#define DD 64
#define BSZ 16
#define TSTEP 12
#define JSPLIT 4
#define JPW 24   /* 96 / JSPLIT */
#define ITILES 6

// workspace offsets (bytes)
#define OFF_HALL  0u           /* 13 slots * 393216 = 5111808 (slot 0 unused) */
#define OFF_E     5111808u     /* 73728 */
#define OFF_S0    5185536u     /* 393216 */
#define OFF_S1    5578752u     /* 393216 */
#define OFF_R0    5971968u     /* 393216 */
#define OFF_R1    6365184u     /* 393216 */
#define OFF_PART  6758400u     /* 4*393216 = 1572864 */
#define OFF_WSWZ  9904128u     /* 73728 */
#define OFF_CNT   9977856u     /* 12*96*4 = 4608 */
#define HSLOT     98304        /* floats per hidden slot */

union fragU  { short8 s; bf16x8 b; };
union packU  { floatx4 f; unsigned long long u[2]; };

static __device__ __forceinline__ short f2bf(float f){
    union { float f; unsigned u; } v; v.f = f;
    unsigned u = v.u;
    u += 0x7fffu + ((u >> 16) & 1u);   // RNE
    return (short)(u >> 16);
}
// inputs provably bounded (|h|<=1, 0.05-scale weights) -> no clamps needed
static __device__ __forceinline__ float fast_tanh(float x){
    float p = __expf(2.f * x);
    return (p - 1.f) * __builtin_amdgcn_rcpf(p + 1.f);
}
static __device__ __forceinline__ float fast_sigmoid(float x){
    float p = __expf(-x);
    return __builtin_amdgcn_rcpf(1.f + p);
}
static __device__ __forceinline__ void zero4(floatx4* a){
    floatx4 z = {0.f,0.f,0.f,0.f};
    a[0]=z; a[1]=z; a[2]=z; a[3]=z;
}
// agent-scope (device-coherent) 16B load/store — R6-validated handoff primitive
static __device__ __forceinline__ floatx4 aload4(const float* p){
    const unsigned long long* s = (const unsigned long long*)p;
    packU pk;
    pk.u[0] = __hip_atomic_load(s,     __ATOMIC_RELAXED, __HIP_MEMORY_SCOPE_AGENT);
    pk.u[1] = __hip_atomic_load(s + 1, __ATOMIC_RELAXED, __HIP_MEMORY_SCOPE_AGENT);
    return pk.f;
}
static __device__ __forceinline__ void astore4(float* p, floatx4 v){
    unsigned long long* d = (unsigned long long*)p;
    packU pk; pk.f = v;
    __hip_atomic_store(d,     pk.u[0], __ATOMIC_RELAXED, __HIP_MEMORY_SCOPE_AGENT);
    __hip_atomic_store(d + 1, pk.u[1], __ATOMIC_RELAXED, __HIP_MEMORY_SCOPE_AGENT);
}
// read A-fragments (16x64, row m = lane&15, k = quad*8+jj) from LDS tile stride 68
static __device__ __forceinline__ void buildA(const float* sM, int col, int quad, short8& a0, short8& a1){
    floatx4 f0 = *(const floatx4*)&sM[col*68 + quad*8];
    floatx4 f1 = *(const floatx4*)&sM[col*68 + quad*8 + 4];
    floatx4 f2 = *(const floatx4*)&sM[col*68 + 32 + quad*8];
    floatx4 f3 = *(const floatx4*)&sM[col*68 + 32 + quad*8 + 4];
    fragU u0, u1;
    #pragma unroll
    for (int jj = 0; jj < 4; jj++){
        u0.b[jj]   = (__bf16)f0[jj];
        u0.b[4+jj] = (__bf16)f1[jj];
        u1.b[jj]   = (__bf16)f2[jj];
        u1.b[4+jj] = (__bf16)f3[jj];
    }
    a0 = u0.s; a1 = u1.s;
}
// 16x64 = (16x64) @ (64x64), B pre-swizzled fragment-major
static __device__ __forceinline__ void mm16(short8 a0, short8 a1, const short8* wzm, int l, floatx4* acc){
    #pragma unroll
    for (int nt = 0; nt < 4; nt++){
        short8 b0 = wzm[nt*64 + l];
        short8 b1 = wzm[(4 + nt)*64 + l];
        acc[nt] = __builtin_amdgcn_mfma_f32_16x16x32_bf16(a0, b0, acc[nt], 0, 0, 0);
        acc[nt] = __builtin_amdgcn_mfma_f32_16x16x32_bf16(a1, b1, acc[nt], 0, 0, 0);
    }
}
// mm16 with preloaded B fragments
static __device__ __forceinline__ void mm16r(short8 a0, short8 a1, const short8* f, floatx4* acc){
    #pragma unroll
    for (int nt = 0; nt < 4; nt++){
        acc[nt] = __builtin_amdgcn_mfma_f32_16x16x32_bf16(a0, f[nt],     acc[nt], 0, 0, 0);
        acc[nt] = __builtin_amdgcn_mfma_f32_16x16x32_bf16(a1, f[4 + nt], acc[nt], 0, 0, 0);
    }
}
// build a B-fragment on the fly from global fp32 W (identical swizzle+f2bf as k_init)
static __device__ __forceinline__ short8 fragB(const float* W, int l, int kc, int nt, int koff){
    short8 r;
    int kbase = koff + kc*32 + ((l >> 4) << 3);
    int n = nt*16 + (l & 15);
    #pragma unroll
    for (int jj = 0; jj < 8; jj++) r[jj] = f2bf(W[(kbase + jj)*64 + n]);
    return r;
}
// mm16 with B built on the fly from global W (bit-identical to pre-swizzled path)
static __device__ __forceinline__ void mm16g(short8 a0, short8 a1, const float* W, int koff, int l, floatx4* acc){
    #pragma unroll
    for (int nt = 0; nt < 4; nt++){
        short8 b0 = fragB(W, l, 0, nt, koff);
        short8 b1 = fragB(W, l, 1, nt, koff);
        acc[nt] = __builtin_amdgcn_mfma_f32_16x16x32_bf16(a0, b0, acc[nt], 0, 0, 0);
        acc[nt] = __builtin_amdgcn_mfma_f32_16x16x32_bf16(a1, b1, acc[nt], 0, 0, 0);
    }
}

// ---------------------------------------------------------------------------
// init + step0 merged. grid 312 = 72(E+cnt) + 144(swizzle) + 96(step0).
// Step0 blocks are SELF-CONTAINED (no dependence on init blocks): they
// compute their 3 E-rows with the identical MAC loop and build B-fragments
// directly from global weights with the identical swizzle+f2bf — bit-exact.
// At t=0, S=R=0 so every edge message equals msgv = tanh(tanh(b1)@Wmsg2+b2)
// and agg[i] = rowsum(adj[i])/96 * msgv; then GRU(0) with h=0 -> h(1), S1, R1.
// ---------------------------------------------------------------------------
__global__ __launch_bounds__(256) void k_init(
    const float* __restrict__ emb, const float* __restrict__ Wmsg1,
    const float* __restrict__ Wmsg2,
    const float* __restrict__ Whr, const float* __restrict__ Whi, const float* __restrict__ Whh,
    const float* __restrict__ Wir, const float* __restrict__ bir,
    const float* __restrict__ Wii, const float* __restrict__ bii,
    const float* __restrict__ Win, const float* __restrict__ bin,
    const float* __restrict__ Wo1, const float* __restrict__ Wo2, const float* __restrict__ Wo3,
    const float* __restrict__ adj, const float* __restrict__ b1in, const float* __restrict__ b2in,
    const int* __restrict__ skills,
    int* __restrict__ cnt, float* __restrict__ Ef, ushort_t* __restrict__ wswz,
    float* __restrict__ hall, float* __restrict__ S1, float* __restrict__ R1)
{
    __shared__ float sM[16*68];
    __shared__ float sG[3][16*68];
    __shared__ float sE[3*64];
    __shared__ float sRS[16*17];

    int wg = blockIdx.x, tid = threadIdx.x;
    if (wg < 72) {                        // E matrices: 3 * 96 * 64
        int flat = wg*256 + tid;
        int m = flat / 6144; int r = flat % 6144; int s = r >> 6; int d = r & 63;
        const float* W = (m==0)? Wir : (m==1)? Wii : Win;
        const float* B = (m==0)? bir : (m==1)? bii : bin;
        float acc = B[d];
        #pragma unroll 8
        for (int k = 0; k < 64; k++)
            acc += emb[s*64 + k] * W[k*64 + d];
        Ef[flat] = acc;
        if (wg < 5) {
            int c = wg*256 + tid;
            if (c < TSTEP*BSZ*ITILES) cnt[c] = 0;
        }
        return;
    }
    if (wg < 216) {                       // swizzle: 9 * 4096
        int flat = (wg - 72)*256 + tid;
        int m = flat >> 12; int q = flat & 4095;
        int jj = q & 7, lane = (q >> 3) & 63, nt = (q >> 9) & 3, kc = q >> 11;
        int k = kc*32 + ((lane >> 4) << 3) + jj;
        int n = nt*16 + (lane & 15);
        const float* src; int idx = k*64 + n;
        switch (m) {
          case 0: src = Wmsg2; break;
          case 1: src = Whr;  break;
          case 2: src = Whi;  break;
          case 3: src = Whh;  break;
          case 4: src = Wmsg1; break;
          case 5: src = Wmsg1; idx = (64 + k)*64 + n; break;
          case 6: src = Wo1; break;
          case 7: src = Wo2; break;
          default: src = Wo3; break;
        }
        wswz[flat] = (ushort_t)f2bf(src[idx]);
        return;
    }

    // ---------------- step0 (self-contained) ----------------
    int tile = wg - 216; int b = tile / 6, it = tile % 6;
    int w = tid >> 6; int l = tid & 63;
    int quad = l >> 4, col = l & 15;

    {   // rowsum(adj): thread (i, seg) sums 6 j's; reduce 16 partials per row
        int i = tid >> 4, seg = tid & 15;
        const float* arow = &adj[(b*NN + it*16 + i)*NN + seg*6];
        float s = 0.f;
        #pragma unroll
        for (int j = 0; j < 6; j++) s += arow[j];
        sRS[i*17 + seg] = s;
    }
    if (tid < 192) {                      // E rows, identical MAC order to Ef path
        int m = tid >> 6, d = tid & 63;
        int s = skills[b*13 + 0];
        const float* W = (m==0)? Wir : (m==1)? Wii : Win;
        const float* B = (m==0)? bir : (m==1)? bii : bin;
        float acc = B[d];
        #pragma unroll 8
        for (int k = 0; k < 64; k++)
            acc += emb[s*64 + k] * W[k*64 + d];
        sE[tid] = acc;
    }
    __syncthreads();
    if (tid < 16) {
        float s = 0.f;
        #pragma unroll
        for (int q = 0; q < 16; q++) s += sRS[tid*17 + q];
        sRS[tid*17 + 16] = s * (1.f/96.f);
    }
    __syncthreads();

    // wave 0: msgv via the standard msg pipeline on broadcast rows, -> sM
    if (w == 0) {
        float b2v[4];
        #pragma unroll
        for (int nt = 0; nt < 4; nt++) b2v[nt] = b2in[nt*16 + col];
        fragU u0, u1;
        #pragma unroll
        for (int e = 0; e < 8; e++) {
            u0.b[e] = (__bf16)fast_tanh(b1in[quad*8 + e]);
            u1.b[e] = (__bf16)fast_tanh(b1in[32 + quad*8 + e]);
        }
        floatx4 acc[4];
        zero4(acc);
        mm16g(u0.s, u1.s, Wmsg2, 0, l, acc);
        #pragma unroll
        for (int nt = 0; nt < 4; nt++)
          #pragma unroll
          for (int r = 0; r < 4; r++) {
            float m = fast_tanh(acc[nt][r] + b2v[nt]);
            sM[(quad*4 + r)*68 + nt*16 + col] = sRS[(quad*4 + r)*17 + 16] * m;
          }
    }
    __syncthreads();

    // gates: wave w -> Whr/Whi/Whh (fragments from global, bit-exact)
    if (w < 3) {
        const float* Wg = (w==0)? Whr : (w==1)? Whi : Whh;
        short8 a0, a1;
        buildA(sM, col, quad, a0, a1);
        floatx4 acc[4];
        zero4(acc);
        mm16g(a0, a1, Wg, 0, l, acc);
        #pragma unroll
        for (int nt = 0; nt < 4; nt++)
          #pragma unroll
          for (int r = 0; r < 4; r++)
            sG[w][(quad*4 + r)*68 + nt*16 + col] = acc[nt][r];
    }
    __syncthreads();

    // elementwise GRU with h_old = 0 -> h(1); write sM + hall[1]
    {
        int i = tid >> 4, k4 = (tid & 15)*4;
        float h[4];
        #pragma unroll
        for (int e = 0; e < 4; e++) {
            int d = k4 + e;
            float gi = fast_sigmoid(sE[64 + d] + sG[1][i*68 + d]);
            float gr = fast_sigmoid(sE[d]      + sG[0][i*68 + d]);
            float nv = fast_tanh  (sE[128 + d] + gr * sG[2][i*68 + d]);
            h[e] = (1.f - gi)*nv;
        }
        #pragma unroll
        for (int e = 0; e < 4; e++) sM[i*68 + k4 + e] = h[e];
        floatx4 hv = { h[0], h[1], h[2], h[3] };
        *(floatx4*)&hall[(size_t)1*HSLOT + (b*NN + it*16 + i)*64 + k4] = hv;
    }
    __syncthreads();

    // S (wave 0) / R (wave 1) projections -> S1 / R1 (Wmsg1 rows 0:64 / 64:128)
    if (w < 2) {
        short8 a0, a1;
        buildA(sM, col, quad, a0, a1);
        floatx4 acc[4];
        zero4(acc);
        mm16g(a0, a1, Wmsg1, w*64, l, acc);
        float* dst = (w == 0) ? S1 : R1;
        #pragma unroll
        for (int nt = 0; nt < 4; nt++)
          #pragma unroll
          for (int r = 0; r < 4; r++)
            dst[(b*NN + it*16 + quad*4 + r)*64 + nt*16 + col] = acc[nt][r];
    }
}

// ---------------------------------------------------------------------------
// fused step t (t = 1..11): message+aggregate; partials agent-stored; last
// js-block per (b,it) runs the GRU in-place. JSPLIT=4, 512 threads (8 waves
// x 3 j's). Winner reuses its OWN partial from registers (exact summation
// order preserved). t=11: msg only, plain partial stores (k_out consumes
// across the launch boundary). grid 384 = 4(js) x 16(b) x 6(it).
// ---------------------------------------------------------------------------
__global__ __launch_bounds__(512, 2) void k_step(
    const float* __restrict__ adj, const float* __restrict__ b1in, const float* __restrict__ b2in,
    const float* __restrict__ Sread, const float* __restrict__ Rread,
    const ushort_t* __restrict__ wswz, float* __restrict__ partial,
    const int* __restrict__ skills, const float* __restrict__ Ef,
    const float* __restrict__ hprev, float* __restrict__ hcur,
    float* __restrict__ Swrite, float* __restrict__ Rwrite,
    int* __restrict__ cnt, int t)
{
    __shared__ float lds[11712];
    __shared__ int sLast;
    float* sS   = lds;          // 24*64  = 1536
    float* sRB  = lds + 1536;   // 16*68  = 1088
    float* sAdj = lds + 2624;   // 16*24  = 384
    float* sAgg = lds + 3008;   // 8*1088 = 8704

    int wg = blockIdx.x;
    int js = wg / 96; int rem = wg % 96; int b = rem / 6; int it = rem % 6;
    int tid = threadIdx.x; int w = tid >> 6; int l = tid & 63;
    int quad = l >> 4, col = l & 15;
    int j0 = js * JPW;
    floatx4 myp;                // this block's scaled partial (tid<256)

    for (int q = tid; q < JPW*16; q += 512) {
        int row = q >> 4, c4 = (q & 15) * 4;
        *(floatx4*)&sS[row*64 + c4] = *(const floatx4*)&Sread[(b*NN + j0 + row)*64 + c4];
    }
    if (tid < 256) {
        int row = tid >> 4, c4 = (tid & 15) * 4;
        floatx4 r4 = *(const floatx4*)&Rread[(b*NN + it*16 + row)*64 + c4];
        floatx4 b4 = *(const floatx4*)&b1in[c4];
        floatx4 o = r4 + b4;
        *(floatx4*)&sRB[row*68 + c4] = o;
    }
    if (tid < 16*JPW) {
        int i = tid / JPW, j = tid % JPW;
        sAdj[tid] = adj[(b*NN + it*16 + i)*NN + j0 + j];
    }
    const short8* wz = (const short8*)wswz;   // matrix 0 = Wmsg2
    short8 w2f[2][4];
    #pragma unroll
    for (int kc = 0; kc < 2; kc++)
      #pragma unroll
      for (int nt = 0; nt < 4; nt++)
        w2f[kc][nt] = wz[(kc*4 + nt)*64 + l];
    float b2v[4];
    #pragma unroll
    for (int nt = 0; nt < 4; nt++) b2v[nt] = b2in[nt*16 + col];
    __syncthreads();

    float rbv[16];
    #pragma unroll
    for (int c = 0; c < 4; c++)
        *(floatx4*)&rbv[c*4] = *(const floatx4*)&sRB[col*68 + (c>>1)*32 + quad*8 + (c&1)*4];

    float agg[4][4];
    #pragma unroll
    for (int nt=0;nt<4;nt++)
      #pragma unroll
      for (int r=0;r<4;r++) agg[nt][r] = 0.f;

    #pragma unroll
    for (int c = 0; c < 3; c++) {
        int jl = w*3 + c;
        float sv[16];
        #pragma unroll
        for (int cc = 0; cc < 4; cc++)
            *(floatx4*)&sv[cc*4] = *(const floatx4*)&sS[jl*64 + (cc>>1)*32 + quad*8 + (cc&1)*4];
        fragU u0, u1;
        #pragma unroll
        for (int e = 0; e < 8; e++) {
            u0.b[e] = (__bf16)fast_tanh(sv[e]   + rbv[e]);
            u1.b[e] = (__bf16)fast_tanh(sv[8+e] + rbv[8+e]);
        }
        floatx4 acc[4];
        zero4(acc);
        #pragma unroll
        for (int nt = 0; nt < 4; nt++) {
            acc[nt] = __builtin_amdgcn_mfma_f32_16x16x32_bf16(u0.s, w2f[0][nt], acc[nt], 0,0,0);
            acc[nt] = __builtin_amdgcn_mfma_f32_16x16x32_bf16(u1.s, w2f[1][nt], acc[nt], 0,0,0);
        }
        float adjv[4];
        #pragma unroll
        for (int r = 0; r < 4; r++) adjv[r] = sAdj[(quad*4 + r)*JPW + jl];
        #pragma unroll
        for (int nt = 0; nt < 4; nt++)
          #pragma unroll
          for (int r = 0; r < 4; r++)
            agg[nt][r] += adjv[r] * fast_tanh(acc[nt][r] + b2v[nt]);
    }
    #pragma unroll
    for (int nt = 0; nt < 4; nt++)
      #pragma unroll
      for (int r = 0; r < 4; r++)
        sAgg[w*1088 + (quad*4 + r)*68 + nt*16 + col] = agg[nt][r];
    __syncthreads();
    if (tid < 256) {
        int i = tid >> 4, k4 = (tid & 15) * 4;
        floatx4 o = {0.f,0.f,0.f,0.f};
        #pragma unroll
        for (int s8 = 0; s8 < 8; s8++)
            o += *(const floatx4*)&sAgg[s8*1088 + i*68 + k4];
        o = o * (1.f/96.f);
        myp = o;
        float* dstp = &partial[((js*BSZ + b)*NN + it*16 + i)*64 + k4];
        if (t == TSTEP - 1) *(floatx4*)dstp = o;   // k_out reads across boundary
        else                astore4(dstp, o);
    }
    if (t == TSTEP - 1) return;           // k_out performs the final GRU

    __syncthreads();                      // drains agent stores (vmcnt 0)
    if (tid == 0) {
        int old = atomicAdd(&cnt[t*(BSZ*ITILES) + b*ITILES + it], 1);
        sLast = (old == JSPLIT - 1);
    }
    __syncthreads();
    if (!sLast) return;

    // ------------------- winner GRU for tile (b, it) ------------------------
    float* sM = lds;          // 16*68 = 1088
    float* sG = lds + 1088;   // 3*1088 = 3264
    float* sH = lds + 4352;   // 16*64 = 1024
    float* sE = lds + 5376;   // 192

    const short8* wzb = (const short8*)wswz;
    short8 fG[8], fSR[8];
    if (w < 3) {
        #pragma unroll
        for (int q = 0; q < 8; q++) fG[q] = wzb[(1 + w)*512 + q*64 + l];
    }
    if (w < 2) {
        #pragma unroll
        for (int q = 0; q < 8; q++) fSR[q] = wzb[(4 + w)*512 + q*64 + l];
    }

    if (tid < 256) {   // phase A: reduce 4 partials (own from regs), fetch h_old
        int i = tid >> 4, k4 = (tid & 15) * 4;
        floatx4 a = {0.f,0.f,0.f,0.f};
        #pragma unroll
        for (int p = 0; p < JSPLIT; p++) {
            if (p == js) a += myp;   // bit-exact: same position in the sum
            else         a += aload4(&partial[((p*BSZ + b)*NN + it*16 + i)*64 + k4]);
        }
        *(floatx4*)&sM[i*68 + k4] = a;
        *(floatx4*)&sH[i*64 + k4] = *(const floatx4*)&hprev[(b*NN + it*16 + i)*64 + k4];
    } else if (tid < 448) {
        int q = tid - 256;
        int s = skills[b*13 + t];
        sE[q] = Ef[(q >> 6)*6144 + s*64 + (q & 63)];
    }
    __syncthreads();

    // phase B: gate matmuls (wave w -> Whr, Whi, Whh)
    if (w < 3) {
        short8 a0, a1;
        buildA(sM, col, quad, a0, a1);
        floatx4 acc[4];
        zero4(acc);
        mm16r(a0, a1, fG, acc);
        #pragma unroll
        for (int nt = 0; nt < 4; nt++)
          #pragma unroll
          for (int r = 0; r < 4; r++)
            sG[w*1088 + (quad*4 + r)*68 + nt*16 + col] = acc[nt][r];
    }
    __syncthreads();

    // phase C: elementwise GRU, hnew -> sM + hcur
    if (tid < 256) {
        int i = tid >> 4, k4 = (tid & 15) * 4;
        float h[4];
        #pragma unroll
        for (int e = 0; e < 4; e++) {
            int d = k4 + e;
            float gr = fast_sigmoid(sE[d]       + sG[0*1088 + i*68 + d]);
            float gi = fast_sigmoid(sE[64 + d]  + sG[1*1088 + i*68 + d]);
            float nv = fast_tanh  (sE[128 + d] + gr * sG[2*1088 + i*68 + d]);
            h[e] = (1.f - gi)*nv + gi*sH[i*64 + d];
        }
        #pragma unroll
        for (int e = 0; e < 4; e++) sM[i*68 + k4 + e] = h[e];
        floatx4 hv = { h[0], h[1], h[2], h[3] };
        *(floatx4*)&hcur[(b*NN + it*16 + i)*64 + k4] = hv;
    }
    __syncthreads();

    // phase D: S (wave 0) and R (wave 1) matmuls for next step (ping-pong)
    if (w < 2) {
        short8 a0, a1;
        buildA(sM, col, quad, a0, a1);
        floatx4 acc[4];
        zero4(acc);
        mm16r(a0, a1, fSR, acc);
        float* dst = (w == 0) ? Swrite : Rwrite;
        #pragma unroll
        for (int nt = 0; nt < 4; nt++)
          #pragma unroll
          for (int r = 0; r < 4; r++)
            dst[(b*NN + it*16 + quad*4 + r)*64 + nt*16 + col] = acc[nt][r];
    }
}

// ---------------------------------------------------------------------------
// batched output MLP over all steps: 1152 independent 16-row tiles, 4 waves
// per block. ts==11 waves first compute h(12) from partial(t=11) + h(11).
// grid 288 x 256 threads.
// ---------------------------------------------------------------------------
__global__ __launch_bounds__(256) void k_out(
    const int* __restrict__ skills, const float* __restrict__ partial,
    const float* __restrict__ Ef, const float* __restrict__ hall,
    const ushort_t* __restrict__ wswz,
    const float* __restrict__ bo1, const float* __restrict__ bo2, const float* __restrict__ bo3,
    float* __restrict__ out)
{
    __shared__ float sT[4][16*68];
    int tid = threadIdx.x; int w = tid >> 6; int l = tid & 63;
    int quad = l >> 4, col = l & 15;
    int g = blockIdx.x*4 + w;
    int ts = g / 96; int rem = g % 96; int b = rem / 6, it = rem % 6;
    float* sm = sT[w];

    if (ts < 11) {
        const float* hsrc = hall + (size_t)(ts + 1)*HSLOT + (b*NN + it*16)*64;
        int i = l >> 2, c0 = (l & 3)*16;
        #pragma unroll
        for (int cc = 0; cc < 4; cc++)
            *(floatx4*)&sm[i*68 + c0 + cc*4] = *(const floatx4*)&hsrc[i*64 + c0 + cc*4];
    } else {
        // final GRU: reduce 4 partials into sm, gates, elementwise vs h(11)
        int i = l >> 2, c0 = (l & 3)*16;
        floatx4 a[4]; zero4(a);
        for (int p = 0; p < JSPLIT; p++) {
            const float* base = &partial[((p*BSZ + b)*NN + it*16 + i)*64 + c0];
            #pragma unroll
            for (int cc = 0; cc < 4; cc++) a[cc] += *(const floatx4*)&base[cc*4];
        }
        #pragma unroll
        for (int cc = 0; cc < 4; cc++) *(floatx4*)&sm[i*68 + c0 + cc*4] = a[cc];

        short8 a0, a1; buildA(sm, col, quad, a0, a1);
        floatx4 Ar[4], Ai[4], Ah[4];
        zero4(Ar); zero4(Ai); zero4(Ah);
        mm16(a0, a1, (const short8*)wswz + 1*512, l, Ar);
        mm16(a0, a1, (const short8*)wswz + 2*512, l, Ai);
        mm16(a0, a1, (const short8*)wswz + 3*512, l, Ah);
        int s = skills[b*13 + 11];
        const float* hp = hall + 11*(size_t)HSLOT;
        #pragma unroll
        for (int nt = 0; nt < 4; nt++) {
            int d = nt*16 + col;
            float er = Ef[0*6144 + s*64 + d];
            float ei = Ef[1*6144 + s*64 + d];
            float en = Ef[2*6144 + s*64 + d];
            #pragma unroll
            for (int r = 0; r < 4; r++) {
                int row = it*16 + quad*4 + r;
                float gr = fast_sigmoid(er + Ar[nt][r]);
                float gi = fast_sigmoid(ei + Ai[nt][r]);
                float nv = fast_tanh  (en + gr*Ah[nt][r]);
                sm[(quad*4 + r)*68 + d] = (1.f - gi)*nv + gi*hp[(b*NN + row)*64 + d];
            }
        }
    }

    float bv1[4], bv2[4], bv3[4];
    #pragma unroll
    for (int nt = 0; nt < 4; nt++) {
        bv1[nt] = bo1[nt*16 + col];
        bv2[nt] = bo2[nt*16 + col];
        bv3[nt] = bo3[nt*16 + col];
    }
    short8 a0, a1;
    floatx4 acc[4];

    buildA(sm, col, quad, a0, a1);
    zero4(acc);
    mm16(a0, a1, (const short8*)wswz + 6*512, l, acc);
    #pragma unroll
    for (int nt = 0; nt < 4; nt++)
      #pragma unroll
      for (int r = 0; r < 4; r++)
        sm[(quad*4 + r)*68 + nt*16 + col] = fmaxf(0.f, acc[nt][r] + bv1[nt]);

    buildA(sm, col, quad, a0, a1);
    zero4(acc);
    mm16(a0, a1, (const short8*)wswz + 7*512, l, acc);
    #pragma unroll
    for (int nt = 0; nt < 4; nt++)
      #pragma unroll
      for (int r = 0; r < 4; r++)
        sm[(quad*4 + r)*68 + nt*16 + col] = fmaxf(0.f, acc[nt][r] + bv2[nt]);

    buildA(sm, col, quad, a0, a1);
    zero4(acc);
    mm16(a0, a1, (const short8*)wswz + 8*512, l, acc);
    #pragma unroll
    for (int nt = 0; nt < 4; nt++)
      #pragma unroll
      for (int r = 0; r < 4; r++)
        out[((b*TSTEP + ts)*NN + it*16 + quad*4 + r)*64 + nt*16 + col] = acc[nt][r] + bv3[nt];
}

extern "C" void kernel_launch(void* const* d_in, const int* in_sizes, int n_in,
                              void* d_out, int out_size, void* d_ws, size_t ws_size,
                              hipStream_t stream) {
    const int*   skills = (const int*)d_in[0];
    const float* adj    = (const float*)d_in[1];
    const float* emb    = (const float*)d_in[2];
    const float* Wmsg1  = (const float*)d_in[3];
    const float* b1     = (const float*)d_in[4];
    const float* Wmsg2  = (const float*)d_in[5];
    const float* b2     = (const float*)d_in[6];
    const float* Whr    = (const float*)d_in[7];
    const float* Whi    = (const float*)d_in[8];
    const float* Whh    = (const float*)d_in[9];
    const float* Wir    = (const float*)d_in[10];
    const float* bir    = (const float*)d_in[11];
    const float* Wii    = (const float*)d_in[12];
    const float* bii    = (const float*)d_in[13];
    const float* Win    = (const float*)d_in[14];
    const float* bin    = (const float*)d_in[15];
    const float* Wo1    = (const float*)d_in[16];
    const float* bo1    = (const float*)d_in[17];
    const float* Wo2    = (const float*)d_in[18];
    const float* bo2    = (const float*)d_in[19];
    const float* Wo3    = (const float*)d_in[20];
    const float* bo3    = (const float*)d_in[21];

    char* ws = (char*)d_ws;
    float*    hall    = (float*)(ws + OFF_HALL);
    float*    Ef      = (float*)(ws + OFF_E);
    float*    S0      = (float*)(ws + OFF_S0);
    float*    S1      = (float*)(ws + OFF_S1);
    float*    R0      = (float*)(ws + OFF_R0);
    float*    R1      = (float*)(ws + OFF_R1);
    float*    partial = (float*)(ws + OFF_PART);
    ushort_t* wswz    = (ushort_t*)(ws + OFF_WSWZ);
    int*      cnt     = (int*)(ws + OFF_CNT);
    float*    out     = (float*)d_out;

    k_init<<<dim3(312), dim3(256), 0, stream>>>(emb, Wmsg1, Wmsg2, Whr, Whi, Whh,
        Wir, bir, Wii, bii, Win, bin, Wo1, Wo2, Wo3,
        adj, b1, b2, skills, cnt, Ef, wswz, hall, S1, R1);

    for (int t = 1; t < TSTEP; t++) {
        const float* Sr = (t & 1) ? S1 : S0;
        const float* Rr = (t & 1) ? R1 : R0;
        float*       Sw = (t & 1) ? S0 : S1;
        float*       Rw = (t & 1) ? R0 : R1;
        k_step<<<dim3(JSPLIT*BSZ*ITILES), dim3(512), 0, stream>>>(
            adj, b1, b2, Sr, Rr, wswz, partial, skills, Ef,
            hall + (size_t)t*HSLOT, hall + (size_t)(t+1)*HSLOT,
            Sw, Rw, cnt, t);
    }
    k_out<<<dim3(288), dim3(256), 0, stream>>>(skills, partial, Ef, hall, wswz,
        bo1, bo2, bo3, out);
}

// Round 15
// 252.768 us; speedup vs baseline: 1.0032x; 1.0032x over previous
//
#include <hip/hip_runtime.h>

typedef unsigned short ushort_t;
typedef __attribute__((ext_vector_type(8))) short short8;
typedef __attribute__((ext_vector_type(8))) __bf16 bf16x8;
typedef __attribute__((ext_vector_type(4))) float floatx4;

#define NN 96
#define DD 64
#define BSZ 16
#define TSTEP 12
#define JSPLIT 4
#define JPW 24   /* 96 / JSPLIT */
#define ITILES 6

// workspace offsets (bytes)
#define OFF_HALL  0u           /* 13 slots * 393216 = 5111808 (slot 0 unused) */
#define OFF_E     5111808u     /* 73728 */
#define OFF_S0    5185536u     /* 393216 */
#define OFF_S1    5578752u     /* 393216 */
#define OFF_R0    5971968u     /* 393216 */
#define OFF_R1    6365184u     /* 393216 */
#define OFF_PART  6758400u     /* 4*393216 = 1572864 */
#define OFF_WSWZ  9904128u     /* 73728 */
#define OFF_CNT   9977856u     /* 12*96*4 = 4608 */
#define HSLOT     98304        /* floats per hidden slot */

union fragU  { short8 s; bf16x8 b; };
union packU  { floatx4 f; unsigned long long u[2]; };

static __device__ __forceinline__ short f2bf(float f){
    union { float f; unsigned u; } v; v.f = f;
    unsigned u = v.u;
    u += 0x7fffu + ((u >> 16) & 1u);   // RNE
    return (short)(u >> 16);
}
// inputs provably bounded (|h|<=1, 0.05-scale weights) -> no clamps needed
static __device__ __forceinline__ float fast_tanh(float x){
    float p = __expf(2.f * x);
    return (p - 1.f) * __builtin_amdgcn_rcpf(p + 1.f);
}
static __device__ __forceinline__ float fast_sigmoid(float x){
    float p = __expf(-x);
    return __builtin_amdgcn_rcpf(1.f + p);
}
static __device__ __forceinline__ void zero4(floatx4* a){
    floatx4 z = {0.f,0.f,0.f,0.f};
    a[0]=z; a[1]=z; a[2]=z; a[3]=z;
}
// agent-scope (device-coherent) 16B load/store — R6-validated handoff primitive
static __device__ __forceinline__ floatx4 aload4(const float* p){
    const unsigned long long* s = (const unsigned long long*)p;
    packU pk;
    pk.u[0] = __hip_atomic_load(s,     __ATOMIC_RELAXED, __HIP_MEMORY_SCOPE_AGENT);
    pk.u[1] = __hip_atomic_load(s + 1, __ATOMIC_RELAXED, __HIP_MEMORY_SCOPE_AGENT);
    return pk.f;
}
static __device__ __forceinline__ void astore4(float* p, floatx4 v){
    unsigned long long* d = (unsigned long long*)p;
    packU pk; pk.f = v;
    __hip_atomic_store(d,     pk.u[0], __ATOMIC_RELAXED, __HIP_MEMORY_SCOPE_AGENT);
    __hip_atomic_store(d + 1, pk.u[1], __ATOMIC_RELAXED, __HIP_MEMORY_SCOPE_AGENT);
}
// read A-fragments (16x64, row m = lane&15, k = quad*8+jj) from LDS tile stride 68
static __device__ __forceinline__ void buildA(const float* sM, int col, int quad, short8& a0, short8& a1){
    floatx4 f0 = *(const floatx4*)&sM[col*68 + quad*8];
    floatx4 f1 = *(const floatx4*)&sM[col*68 + quad*8 + 4];
    floatx4 f2 = *(const floatx4*)&sM[col*68 + 32 + quad*8];
    floatx4 f3 = *(const floatx4*)&sM[col*68 + 32 + quad*8 + 4];
    fragU u0, u1;
    #pragma unroll
    for (int jj = 0; jj < 4; jj++){
        u0.b[jj]   = (__bf16)f0[jj];
        u0.b[4+jj] = (__bf16)f1[jj];
        u1.b[jj]   = (__bf16)f2[jj];
        u1.b[4+jj] = (__bf16)f3[jj];
    }
    a0 = u0.s; a1 = u1.s;
}
// 16x64 = (16x64) @ (64x64), B pre-swizzled fragment-major
static __device__ __forceinline__ void mm16(short8 a0, short8 a1, const short8* wzm, int l, floatx4* acc){
    #pragma unroll
    for (int nt = 0; nt < 4; nt++){
        short8 b0 = wzm[nt*64 + l];
        short8 b1 = wzm[(4 + nt)*64 + l];
        acc[nt] = __builtin_amdgcn_mfma_f32_16x16x32_bf16(a0, b0, acc[nt], 0, 0, 0);
        acc[nt] = __builtin_amdgcn_mfma_f32_16x16x32_bf16(a1, b1, acc[nt], 0, 0, 0);
    }
}
// mm16 with preloaded B fragments
static __device__ __forceinline__ void mm16r(short8 a0, short8 a1, const short8* f, floatx4* acc){
    #pragma unroll
    for (int nt = 0; nt < 4; nt++){
        acc[nt] = __builtin_amdgcn_mfma_f32_16x16x32_bf16(a0, f[nt],     acc[nt], 0, 0, 0);
        acc[nt] = __builtin_amdgcn_mfma_f32_16x16x32_bf16(a1, f[4 + nt], acc[nt], 0, 0, 0);
    }
}
// build a B-fragment on the fly from global fp32 W (identical swizzle+f2bf as k_init)
static __device__ __forceinline__ short8 fragB(const float* W, int l, int kc, int nt, int koff){
    short8 r;
    int kbase = koff + kc*32 + ((l >> 4) << 3);
    int n = nt*16 + (l & 15);
    #pragma unroll
    for (int jj = 0; jj < 8; jj++) r[jj] = f2bf(W[(kbase + jj)*64 + n]);
    return r;
}
// mm16 with B built on the fly from global W (bit-identical to pre-swizzled path)
static __device__ __forceinline__ void mm16g(short8 a0, short8 a1, const float* W, int koff, int l, floatx4* acc){
    #pragma unroll
    for (int nt = 0; nt < 4; nt++){
        short8 b0 = fragB(W, l, 0, nt, koff);
        short8 b1 = fragB(W, l, 1, nt, koff);
        acc[nt] = __builtin_amdgcn_mfma_f32_16x16x32_bf16(a0, b0, acc[nt], 0, 0, 0);
        acc[nt] = __builtin_amdgcn_mfma_f32_16x16x32_bf16(a1, b1, acc[nt], 0, 0, 0);
    }
}
// single-wave 3-layer output MLP on a 16x68 LDS tile (identical to k_out body)
static __device__ __forceinline__ void mlp_tile(
    float* sm, const ushort_t* wswz,
    const float* bo1, const float* bo2, const float* bo3,
    float* out, int b, int ts, int it, int l, int quad, int col)
{
    float bv1[4], bv2[4], bv3[4];
    #pragma unroll
    for (int nt = 0; nt < 4; nt++) {
        bv1[nt] = bo1[nt*16 + col];
        bv2[nt] = bo2[nt*16 + col];
        bv3[nt] = bo3[nt*16 + col];
    }
    short8 a0, a1;
    floatx4 acc[4];

    buildA(sm, col, quad, a0, a1);
    zero4(acc);
    mm16(a0, a1, (const short8*)wswz + 6*512, l, acc);
    #pragma unroll
    for (int nt = 0; nt < 4; nt++)
      #pragma unroll
      for (int r = 0; r < 4; r++)
        sm[(quad*4 + r)*68 + nt*16 + col] = fmaxf(0.f, acc[nt][r] + bv1[nt]);

    buildA(sm, col, quad, a0, a1);
    zero4(acc);
    mm16(a0, a1, (const short8*)wswz + 7*512, l, acc);
    #pragma unroll
    for (int nt = 0; nt < 4; nt++)
      #pragma unroll
      for (int r = 0; r < 4; r++)
        sm[(quad*4 + r)*68 + nt*16 + col] = fmaxf(0.f, acc[nt][r] + bv2[nt]);

    buildA(sm, col, quad, a0, a1);
    zero4(acc);
    mm16(a0, a1, (const short8*)wswz + 8*512, l, acc);
    #pragma unroll
    for (int nt = 0; nt < 4; nt++)
      #pragma unroll
      for (int r = 0; r < 4; r++)
        out[((b*TSTEP + ts)*NN + it*16 + quad*4 + r)*64 + nt*16 + col] = acc[nt][r] + bv3[nt];
}

// ---------------------------------------------------------------------------
// init + step0 merged. grid 312 = 72(E+cnt) + 144(swizzle) + 96(step0).
// Step0 blocks are SELF-CONTAINED: identical MAC loop for their E-rows and
// on-the-fly B-fragments (identical swizzle+f2bf) — bit-exact. At t=0,
// S=R=0 so every edge message equals msgv = tanh(tanh(b1)@Wmsg2+b2) and
// agg[i] = rowsum(adj[i])/96 * msgv; GRU(0) with h=0 -> h(1), S1, R1.
// ---------------------------------------------------------------------------
__global__ __launch_bounds__(256) void k_init(
    const float* __restrict__ emb, const float* __restrict__ Wmsg1,
    const float* __restrict__ Wmsg2,
    const float* __restrict__ Whr, const float* __restrict__ Whi, const float* __restrict__ Whh,
    const float* __restrict__ Wir, const float* __restrict__ bir,
    const float* __restrict__ Wii, const float* __restrict__ bii,
    const float* __restrict__ Win, const float* __restrict__ bin,
    const float* __restrict__ Wo1, const float* __restrict__ Wo2, const float* __restrict__ Wo3,
    const float* __restrict__ adj, const float* __restrict__ b1in, const float* __restrict__ b2in,
    const int* __restrict__ skills,
    int* __restrict__ cnt, float* __restrict__ Ef, ushort_t* __restrict__ wswz,
    float* __restrict__ hall, float* __restrict__ S1, float* __restrict__ R1)
{
    __shared__ float sM[16*68];
    __shared__ float sG[3][16*68];
    __shared__ float sE[3*64];
    __shared__ float sRS[16*17];

    int wg = blockIdx.x, tid = threadIdx.x;
    if (wg < 72) {                        // E matrices: 3 * 96 * 64
        int flat = wg*256 + tid;
        int m = flat / 6144; int r = flat % 6144; int s = r >> 6; int d = r & 63;
        const float* W = (m==0)? Wir : (m==1)? Wii : Win;
        const float* B = (m==0)? bir : (m==1)? bii : bin;
        float acc = B[d];
        #pragma unroll 8
        for (int k = 0; k < 64; k++)
            acc += emb[s*64 + k] * W[k*64 + d];
        Ef[flat] = acc;
        if (wg < 5) {
            int c = wg*256 + tid;
            if (c < TSTEP*BSZ*ITILES) cnt[c] = 0;
        }
        return;
    }
    if (wg < 216) {                       // swizzle: 9 * 4096
        int flat = (wg - 72)*256 + tid;
        int m = flat >> 12; int q = flat & 4095;
        int jj = q & 7, lane = (q >> 3) & 63, nt = (q >> 9) & 3, kc = q >> 11;
        int k = kc*32 + ((lane >> 4) << 3) + jj;
        int n = nt*16 + (lane & 15);
        const float* src; int idx = k*64 + n;
        switch (m) {
          case 0: src = Wmsg2; break;
          case 1: src = Whr;  break;
          case 2: src = Whi;  break;
          case 3: src = Whh;  break;
          case 4: src = Wmsg1; break;
          case 5: src = Wmsg1; idx = (64 + k)*64 + n; break;
          case 6: src = Wo1; break;
          case 7: src = Wo2; break;
          default: src = Wo3; break;
        }
        wswz[flat] = (ushort_t)f2bf(src[idx]);
        return;
    }

    // ---------------- step0 (self-contained) ----------------
    int tile = wg - 216; int b = tile / 6, it = tile % 6;
    int w = tid >> 6; int l = tid & 63;
    int quad = l >> 4, col = l & 15;

    {   // rowsum(adj): thread (i, seg) sums 6 j's; reduce 16 partials per row
        int i = tid >> 4, seg = tid & 15;
        const float* arow = &adj[(b*NN + it*16 + i)*NN + seg*6];
        float s = 0.f;
        #pragma unroll
        for (int j = 0; j < 6; j++) s += arow[j];
        sRS[i*17 + seg] = s;
    }
    if (tid < 192) {                      // E rows, identical MAC order to Ef path
        int m = tid >> 6, d = tid & 63;
        int s = skills[b*13 + 0];
        const float* W = (m==0)? Wir : (m==1)? Wii : Win;
        const float* B = (m==0)? bir : (m==1)? bii : bin;
        float acc = B[d];
        #pragma unroll 8
        for (int k = 0; k < 64; k++)
            acc += emb[s*64 + k] * W[k*64 + d];
        sE[tid] = acc;
    }
    __syncthreads();
    if (tid < 16) {
        float s = 0.f;
        #pragma unroll
        for (int q = 0; q < 16; q++) s += sRS[tid*17 + q];
        sRS[tid*17 + 16] = s * (1.f/96.f);
    }
    __syncthreads();

    // wave 0: msgv via the standard msg pipeline on broadcast rows, -> sM
    if (w == 0) {
        float b2v[4];
        #pragma unroll
        for (int nt = 0; nt < 4; nt++) b2v[nt] = b2in[nt*16 + col];
        fragU u0, u1;
        #pragma unroll
        for (int e = 0; e < 8; e++) {
            u0.b[e] = (__bf16)fast_tanh(b1in[quad*8 + e]);
            u1.b[e] = (__bf16)fast_tanh(b1in[32 + quad*8 + e]);
        }
        floatx4 acc[4];
        zero4(acc);
        mm16g(u0.s, u1.s, Wmsg2, 0, l, acc);
        #pragma unroll
        for (int nt = 0; nt < 4; nt++)
          #pragma unroll
          for (int r = 0; r < 4; r++) {
            float m = fast_tanh(acc[nt][r] + b2v[nt]);
            sM[(quad*4 + r)*68 + nt*16 + col] = sRS[(quad*4 + r)*17 + 16] * m;
          }
    }
    __syncthreads();

    // gates: wave w -> Whr/Whi/Whh (fragments from global, bit-exact)
    if (w < 3) {
        const float* Wg = (w==0)? Whr : (w==1)? Whi : Whh;
        short8 a0, a1;
        buildA(sM, col, quad, a0, a1);
        floatx4 acc[4];
        zero4(acc);
        mm16g(a0, a1, Wg, 0, l, acc);
        #pragma unroll
        for (int nt = 0; nt < 4; nt++)
          #pragma unroll
          for (int r = 0; r < 4; r++)
            sG[w][(quad*4 + r)*68 + nt*16 + col] = acc[nt][r];
    }
    __syncthreads();

    // elementwise GRU with h_old = 0 -> h(1); write sM + hall[1]
    {
        int i = tid >> 4, k4 = (tid & 15)*4;
        float h[4];
        #pragma unroll
        for (int e = 0; e < 4; e++) {
            int d = k4 + e;
            float gi = fast_sigmoid(sE[64 + d] + sG[1][i*68 + d]);
            float gr = fast_sigmoid(sE[d]      + sG[0][i*68 + d]);
            float nv = fast_tanh  (sE[128 + d] + gr * sG[2][i*68 + d]);
            h[e] = (1.f - gi)*nv;
        }
        #pragma unroll
        for (int e = 0; e < 4; e++) sM[i*68 + k4 + e] = h[e];
        floatx4 hv = { h[0], h[1], h[2], h[3] };
        *(floatx4*)&hall[(size_t)1*HSLOT + (b*NN + it*16 + i)*64 + k4] = hv;
    }
    __syncthreads();

    // S (wave 0) / R (wave 1) projections -> S1 / R1 (Wmsg1 rows 0:64 / 64:128)
    if (w < 2) {
        short8 a0, a1;
        buildA(sM, col, quad, a0, a1);
        floatx4 acc[4];
        zero4(acc);
        mm16g(a0, a1, Wmsg1, w*64, l, acc);
        float* dst = (w == 0) ? S1 : R1;
        #pragma unroll
        for (int nt = 0; nt < 4; nt++)
          #pragma unroll
          for (int r = 0; r < 4; r++)
            dst[(b*NN + it*16 + quad*4 + r)*64 + nt*16 + col] = acc[nt][r];
    }
}

// ---------------------------------------------------------------------------
// fused step t (t = 1..11): message+aggregate; partials agent-stored; last
// js-block per (b,it) runs the GRU in-place; FIRST-arriving block's wave 0
// computes the output MLP for (b,it,ts=t-1) — hall[t] is complete via the
// previous launch boundary, and this runs concurrent with the winner's GRU
// tail on a different block (zero added critical path). Winner reuses its
// own partial from registers (bit-exact sum order). t=11: msg only, plain
// stores. grid 384 = 4(js) x 16(b) x 6(it), 512 threads.
// ---------------------------------------------------------------------------
__global__ __launch_bounds__(512, 2) void k_step(
    const float* __restrict__ adj, const float* __restrict__ b1in, const float* __restrict__ b2in,
    const float* __restrict__ Sread, const float* __restrict__ Rread,
    const ushort_t* __restrict__ wswz, float* __restrict__ partial,
    const int* __restrict__ skills, const float* __restrict__ Ef,
    const float* __restrict__ hprev, float* __restrict__ hcur,
    float* __restrict__ Swrite, float* __restrict__ Rwrite,
    int* __restrict__ cnt,
    const float* __restrict__ bo1, const float* __restrict__ bo2, const float* __restrict__ bo3,
    float* __restrict__ out, int t)
{
    __shared__ float lds[11712];
    __shared__ int sLast, sFirst;
    float* sS   = lds;          // 24*64  = 1536
    float* sRB  = lds + 1536;   // 16*68  = 1088
    float* sAdj = lds + 2624;   // 16*24  = 384
    float* sAgg = lds + 3008;   // 8*1088 = 8704

    int wg = blockIdx.x;
    int js = wg / 96; int rem = wg % 96; int b = rem / 6; int it = rem % 6;
    int tid = threadIdx.x; int w = tid >> 6; int l = tid & 63;
    int quad = l >> 4, col = l & 15;
    int j0 = js * JPW;
    floatx4 myp;                // this block's scaled partial (tid<256)

    for (int q = tid; q < JPW*16; q += 512) {
        int row = q >> 4, c4 = (q & 15) * 4;
        *(floatx4*)&sS[row*64 + c4] = *(const floatx4*)&Sread[(b*NN + j0 + row)*64 + c4];
    }
    if (tid < 256) {
        int row = tid >> 4, c4 = (tid & 15) * 4;
        floatx4 r4 = *(const floatx4*)&Rread[(b*NN + it*16 + row)*64 + c4];
        floatx4 b4 = *(const floatx4*)&b1in[c4];
        floatx4 o = r4 + b4;
        *(floatx4*)&sRB[row*68 + c4] = o;
    }
    if (tid < 16*JPW) {
        int i = tid / JPW, j = tid % JPW;
        sAdj[tid] = adj[(b*NN + it*16 + i)*NN + j0 + j];
    }
    const short8* wz = (const short8*)wswz;   // matrix 0 = Wmsg2
    short8 w2f[2][4];
    #pragma unroll
    for (int kc = 0; kc < 2; kc++)
      #pragma unroll
      for (int nt = 0; nt < 4; nt++)
        w2f[kc][nt] = wz[(kc*4 + nt)*64 + l];
    float b2v[4];
    #pragma unroll
    for (int nt = 0; nt < 4; nt++) b2v[nt] = b2in[nt*16 + col];
    __syncthreads();

    float rbv[16];
    #pragma unroll
    for (int c = 0; c < 4; c++)
        *(floatx4*)&rbv[c*4] = *(const floatx4*)&sRB[col*68 + (c>>1)*32 + quad*8 + (c&1)*4];

    float agg[4][4];
    #pragma unroll
    for (int nt=0;nt<4;nt++)
      #pragma unroll
      for (int r=0;r<4;r++) agg[nt][r] = 0.f;

    #pragma unroll
    for (int c = 0; c < 3; c++) {
        int jl = w*3 + c;
        float sv[16];
        #pragma unroll
        for (int cc = 0; cc < 4; cc++)
            *(floatx4*)&sv[cc*4] = *(const floatx4*)&sS[jl*64 + (cc>>1)*32 + quad*8 + (cc&1)*4];
        fragU u0, u1;
        #pragma unroll
        for (int e = 0; e < 8; e++) {
            u0.b[e] = (__bf16)fast_tanh(sv[e]   + rbv[e]);
            u1.b[e] = (__bf16)fast_tanh(sv[8+e] + rbv[8+e]);
        }
        floatx4 acc[4];
        zero4(acc);
        #pragma unroll
        for (int nt = 0; nt < 4; nt++) {
            acc[nt] = __builtin_amdgcn_mfma_f32_16x16x32_bf16(u0.s, w2f[0][nt], acc[nt], 0,0,0);
            acc[nt] = __builtin_amdgcn_mfma_f32_16x16x32_bf16(u1.s, w2f[1][nt], acc[nt], 0,0,0);
        }
        float adjv[4];
        #pragma unroll
        for (int r = 0; r < 4; r++) adjv[r] = sAdj[(quad*4 + r)*JPW + jl];
        #pragma unroll
        for (int nt = 0; nt < 4; nt++)
          #pragma unroll
          for (int r = 0; r < 4; r++)
            agg[nt][r] += adjv[r] * fast_tanh(acc[nt][r] + b2v[nt]);
    }
    #pragma unroll
    for (int nt = 0; nt < 4; nt++)
      #pragma unroll
      for (int r = 0; r < 4; r++)
        sAgg[w*1088 + (quad*4 + r)*68 + nt*16 + col] = agg[nt][r];
    __syncthreads();
    if (tid < 256) {
        int i = tid >> 4, k4 = (tid & 15) * 4;
        floatx4 o = {0.f,0.f,0.f,0.f};
        #pragma unroll
        for (int s8 = 0; s8 < 8; s8++)
            o += *(const floatx4*)&sAgg[s8*1088 + i*68 + k4];
        o = o * (1.f/96.f);
        myp = o;
        float* dstp = &partial[((js*BSZ + b)*NN + it*16 + i)*64 + k4];
        if (t == TSTEP - 1) *(floatx4*)dstp = o;   // k_out reads across boundary
        else                astore4(dstp, o);
    }
    if (t == TSTEP - 1) return;           // k_out performs the final GRU (+ ts=10,11 MLP)

    __syncthreads();                      // drains agent stores (vmcnt 0)
    if (tid == 0) {
        int old = atomicAdd(&cnt[t*(BSZ*ITILES) + b*ITILES + it], 1);
        sLast  = (old == JSPLIT - 1);
        sFirst = (old == 0);
    }
    __syncthreads();
    if (!sLast) {
        // first-arriver's wave 0: output MLP for (b, it, ts = t-1) using hall[t]
        if (sFirst && w == 0) {
            float* sm = lds;              // whole block's LDS is free now
            const float* hsrc = hcur - HSLOT + (b*NN + it*16)*64;   // hall[t]
            int i2 = l >> 2, c0 = (l & 3)*16;
            #pragma unroll
            for (int cc = 0; cc < 4; cc++)
                *(floatx4*)&sm[i2*68 + c0 + cc*4] = *(const floatx4*)&hsrc[i2*64 + c0 + cc*4];
            mlp_tile(sm, wswz, bo1, bo2, bo3, out, b, t - 1, it, l, quad, col);
        }
        return;
    }

    // ------------------- winner GRU for tile (b, it) ------------------------
    float* sM = lds;          // 16*68 = 1088
    float* sG = lds + 1088;   // 3*1088 = 3264
    float* sH = lds + 4352;   // 16*64 = 1024
    float* sE = lds + 5376;   // 192

    const short8* wzb = (const short8*)wswz;
    short8 fG[8], fSR[8];
    if (w < 3) {
        #pragma unroll
        for (int q = 0; q < 8; q++) fG[q] = wzb[(1 + w)*512 + q*64 + l];
    }
    if (w < 2) {
        #pragma unroll
        for (int q = 0; q < 8; q++) fSR[q] = wzb[(4 + w)*512 + q*64 + l];
    }

    if (tid < 256) {   // phase A: reduce 4 partials (own from regs), fetch h_old
        int i = tid >> 4, k4 = (tid & 15) * 4;
        floatx4 a = {0.f,0.f,0.f,0.f};
        #pragma unroll
        for (int p = 0; p < JSPLIT; p++) {
            if (p == js) a += myp;   // bit-exact: same position in the sum
            else         a += aload4(&partial[((p*BSZ + b)*NN + it*16 + i)*64 + k4]);
        }
        *(floatx4*)&sM[i*68 + k4] = a;
        *(floatx4*)&sH[i*64 + k4] = *(const floatx4*)&hprev[(b*NN + it*16 + i)*64 + k4];
    } else if (tid < 448) {
        int q = tid - 256;
        int s = skills[b*13 + t];
        sE[q] = Ef[(q >> 6)*6144 + s*64 + (q & 63)];
    }
    __syncthreads();

    // phase B: gate matmuls (wave w -> Whr, Whi, Whh)
    if (w < 3) {
        short8 a0, a1;
        buildA(sM, col, quad, a0, a1);
        floatx4 acc[4];
        zero4(acc);
        mm16r(a0, a1, fG, acc);
        #pragma unroll
        for (int nt = 0; nt < 4; nt++)
          #pragma unroll
          for (int r = 0; r < 4; r++)
            sG[w*1088 + (quad*4 + r)*68 + nt*16 + col] = acc[nt][r];
    }
    __syncthreads();

    // phase C: elementwise GRU, hnew -> sM + hcur
    if (tid < 256) {
        int i = tid >> 4, k4 = (tid & 15) * 4;
        float h[4];
        #pragma unroll
        for (int e = 0; e < 4; e++) {
            int d = k4 + e;
            float gr = fast_sigmoid(sE[d]       + sG[0*1088 + i*68 + d]);
            float gi = fast_sigmoid(sE[64 + d]  + sG[1*1088 + i*68 + d]);
            float nv = fast_tanh  (sE[128 + d] + gr * sG[2*1088 + i*68 + d]);
            h[e] = (1.f - gi)*nv + gi*sH[i*64 + d];
        }
        #pragma unroll
        for (int e = 0; e < 4; e++) sM[i*68 + k4 + e] = h[e];
        floatx4 hv = { h[0], h[1], h[2], h[3] };
        *(floatx4*)&hcur[(b*NN + it*16 + i)*64 + k4] = hv;
    }
    __syncthreads();

    // phase D: S (wave 0) and R (wave 1) matmuls for next step (ping-pong)
    if (w < 2) {
        short8 a0, a1;
        buildA(sM, col, quad, a0, a1);
        floatx4 acc[4];
        zero4(acc);
        mm16r(a0, a1, fSR, acc);
        float* dst = (w == 0) ? Swrite : Rwrite;
        #pragma unroll
        for (int nt = 0; nt < 4; nt++)
          #pragma unroll
          for (int r = 0; r < 4; r++)
            dst[(b*NN + it*16 + quad*4 + r)*64 + nt*16 + col] = acc[nt][r];
    }
}

// ---------------------------------------------------------------------------
// residual output work: ts=10 tiles (MLP only) and ts=11 tiles (final GRU
// from partial(t=11) + h(11), then MLP). 192 tiles, 4 waves per block.
// grid 48 x 256 threads.
// ---------------------------------------------------------------------------
__global__ __launch_bounds__(256) void k_out(
    const int* __restrict__ skills, const float* __restrict__ partial,
    const float* __restrict__ Ef, const float* __restrict__ hall,
    const ushort_t* __restrict__ wswz,
    const float* __restrict__ bo1, const float* __restrict__ bo2, const float* __restrict__ bo3,
    float* __restrict__ out)
{
    __shared__ float sT[4][16*68];
    int tid = threadIdx.x; int w = tid >> 6; int l = tid & 63;
    int quad = l >> 4, col = l & 15;
    int g = blockIdx.x*4 + w;
    int ts = 10 + g / 96; int rem = g % 96; int b = rem / 6, it = rem % 6;
    float* sm = sT[w];

    if (ts == 10) {
        const float* hsrc = hall + (size_t)11*HSLOT + (b*NN + it*16)*64;
        int i = l >> 2, c0 = (l & 3)*16;
        #pragma unroll
        for (int cc = 0; cc < 4; cc++)
            *(floatx4*)&sm[i*68 + c0 + cc*4] = *(const floatx4*)&hsrc[i*64 + c0 + cc*4];
    } else {
        // final GRU: reduce 4 partials into sm, gates, elementwise vs h(11)
        int i = l >> 2, c0 = (l & 3)*16;
        floatx4 a[4]; zero4(a);
        for (int p = 0; p < JSPLIT; p++) {
            const float* base = &partial[((p*BSZ + b)*NN + it*16 + i)*64 + c0];
            #pragma unroll
            for (int cc = 0; cc < 4; cc++) a[cc] += *(const floatx4*)&base[cc*4];
        }
        #pragma unroll
        for (int cc = 0; cc < 4; cc++) *(floatx4*)&sm[i*68 + c0 + cc*4] = a[cc];

        short8 a0, a1; buildA(sm, col, quad, a0, a1);
        floatx4 Ar[4], Ai[4], Ah[4];
        zero4(Ar); zero4(Ai); zero4(Ah);
        mm16(a0, a1, (const short8*)wswz + 1*512, l, Ar);
        mm16(a0, a1, (const short8*)wswz + 2*512, l, Ai);
        mm16(a0, a1, (const short8*)wswz + 3*512, l, Ah);
        int s = skills[b*13 + 11];
        const float* hp = hall + 11*(size_t)HSLOT;
        #pragma unroll
        for (int nt = 0; nt < 4; nt++) {
            int d = nt*16 + col;
            float er = Ef[0*6144 + s*64 + d];
            float ei = Ef[1*6144 + s*64 + d];
            float en = Ef[2*6144 + s*64 + d];
            #pragma unroll
            for (int r = 0; r < 4; r++) {
                int row = it*16 + quad*4 + r;
                float gr = fast_sigmoid(er + Ar[nt][r]);
                float gi = fast_sigmoid(ei + Ai[nt][r]);
                float nv = fast_tanh  (en + gr*Ah[nt][r]);
                sm[(quad*4 + r)*68 + d] = (1.f - gi)*nv + gi*hp[(b*NN + row)*64 + d];
            }
        }
    }
    mlp_tile(sm, wswz, bo1, bo2, bo3, out, b, ts, it, l, quad, col);
}

extern "C" void kernel_launch(void* const* d_in, const int* in_sizes, int n_in,
                              void* d_out, int out_size, void* d_ws, size_t ws_size,
                              hipStream_t stream) {
    const int*   skills = (const int*)d_in[0];
    const float* adj    = (const float*)d_in[1];
    const float* emb    = (const float*)d_in[2];
    const float* Wmsg1  = (const float*)d_in[3];
    const float* b1     = (const float*)d_in[4];
    const float* Wmsg2  = (const float*)d_in[5];
    const float* b2     = (const float*)d_in[6];
    const float* Whr    = (const float*)d_in[7];
    const float* Whi    = (const float*)d_in[8];
    const float* Whh    = (const float*)d_in[9];
    const float* Wir    = (const float*)d_in[10];
    const float* bir    = (const float*)d_in[11];
    const float* Wii    = (const float*)d_in[12];
    const float* bii    = (const float*)d_in[13];
    const float* Win    = (const float*)d_in[14];
    const float* bin    = (const float*)d_in[15];
    const float* Wo1    = (const float*)d_in[16];
    const float* bo1    = (const float*)d_in[17];
    const float* Wo2    = (const float*)d_in[18];
    const float* bo2    = (const float*)d_in[19];
    const float* Wo3    = (const float*)d_in[20];
    const float* bo3    = (const float*)d_in[21];

    char* ws = (char*)d_ws;
    float*    hall    = (float*)(ws + OFF_HALL);
    float*    Ef      = (float*)(ws + OFF_E);
    float*    S0      = (float*)(ws + OFF_S0);
    float*    S1      = (float*)(ws + OFF_S1);
    float*    R0      = (float*)(ws + OFF_R0);
    float*    R1      = (float*)(ws + OFF_R1);
    float*    partial = (float*)(ws + OFF_PART);
    ushort_t* wswz    = (ushort_t*)(ws + OFF_WSWZ);
    int*      cnt     = (int*)(ws + OFF_CNT);
    float*    out     = (float*)d_out;

    k_init<<<dim3(312), dim3(256), 0, stream>>>(emb, Wmsg1, Wmsg2, Whr, Whi, Whh,
        Wir, bir, Wii, bii, Win, bin, Wo1, Wo2, Wo3,
        adj, b1, b2, skills, cnt, Ef, wswz, hall, S1, R1);

    for (int t = 1; t < TSTEP; t++) {
        const float* Sr = (t & 1) ? S1 : S0;
        const float* Rr = (t & 1) ? R1 : R0;
        float*       Sw = (t & 1) ? S0 : S1;
        float*       Rw = (t & 1) ? R0 : R1;
        k_step<<<dim3(JSPLIT*BSZ*ITILES), dim3(512), 0, stream>>>(
            adj, b1, b2, Sr, Rr, wswz, partial, skills, Ef,
            hall + (size_t)t*HSLOT, hall + (size_t)(t+1)*HSLOT,
            Sw, Rw, cnt, bo1, bo2, bo3, out, t);
    }
    k_out<<<dim3(48), dim3(256), 0, stream>>>(skills, partial, Ef, hall, wswz,
        bo1, bo2, bo3, out);
}